// Round 5
// baseline (585.859 us; speedup 1.0000x reference)
//
#include <hip/hip_runtime.h>
#include <hip/hip_bf16.h>

typedef unsigned short u16;
typedef unsigned long long u64;
typedef u16 us8 __attribute__((ext_vector_type(8)));
typedef __bf16 bf8_t __attribute__((ext_vector_type(8)));
typedef float f32x4 __attribute__((ext_vector_type(4)));

__device__ __forceinline__ float b2f(u16 u) {
    return __uint_as_float(((unsigned int)u) << 16);
}
__device__ __forceinline__ u16 f2b(float f) {
    union { __hip_bfloat16 h; u16 u; } v;
    v.h = __float2bfloat16(f);
    return v.u;
}
__device__ __forceinline__ f32x4 mfma16(bf8_t a, bf8_t b, f32x4 c) {
    return __builtin_amdgcn_mfma_f32_16x16x32_bf16(a, b, c, 0, 0, 0);
}
__device__ __forceinline__ void gload_lds16(const u16* g, u16* lds_base) {
    __builtin_amdgcn_global_load_lds((const __attribute__((address_space(1))) unsigned int*)g,
                                     (__attribute__((address_space(3))) unsigned int*)lds_base,
                                     16, 0, 0);
}

// ---------------- fp32 -> bf16 convert (8 elems/thread)
__global__ __launch_bounds__(256) void f32_to_bf16(const float* __restrict__ src,
                                                   u16* __restrict__ dst, int n8) {
    int idx = blockIdx.x * 256 + threadIdx.x;
    if (idx >= n8) return;
    float4 f0 = ((const float4*)src)[idx * 2];
    float4 f1 = ((const float4*)src)[idx * 2 + 1];
    us8 o;
    o[0] = f2b(f0.x); o[1] = f2b(f0.y); o[2] = f2b(f0.z); o[3] = f2b(f0.w);
    o[4] = f2b(f1.x); o[5] = f2b(f1.y); o[6] = f2b(f1.z); o[7] = f2b(f1.w);
    ((us8*)dst)[idx] = o;
}

// ---------------- bf16 MFMA GEMM: C[m,n] = sum_k A[m,k]*B[n,k]; 128x128x32 tiles
template<int STORE_F32>
__global__ __launch_bounds__(256) void gemm_mfma_bt(const u16* __restrict__ A, const u16* __restrict__ B,
                                                    void* __restrict__ Cout, int M, int N, int K, int ldc) {
    __shared__ u16 Alds[128 * 32];
    __shared__ u16 Blds[128 * 32];
    const int tid = threadIdx.x;
    const int lane = tid & 63, wave = tid >> 6;
    const int lm = lane & 15, lq = lane >> 4;
    const int wm = wave >> 1, wn = wave & 1;
    const int m0 = blockIdx.y * 128, n0 = blockIdx.x * 128;
    const int srow = lane >> 2;
    const int scol = (lane & 3) * 8;

    f32x4 acc[4][4] = {};

    for (int k0 = 0; k0 < K; k0 += 32) {
#pragma unroll
        for (int p = 0; p < 2; p++) {
            int rbase = wave * 16 + p * 64;
            gload_lds16(A + (size_t)(m0 + rbase + srow) * K + k0 + scol, &Alds[rbase * 32]);
            gload_lds16(B + (size_t)(n0 + rbase + srow) * K + k0 + scol, &Blds[rbase * 32]);
        }
        __syncthreads();
        bf8_t af[4], bf[4];
#pragma unroll
        for (int mb = 0; mb < 4; mb++)
            af[mb] = *(const bf8_t*)&Alds[(wm * 64 + mb * 16 + lm) * 32 + lq * 8];
#pragma unroll
        for (int nb = 0; nb < 4; nb++)
            bf[nb] = *(const bf8_t*)&Blds[(wn * 64 + nb * 16 + lm) * 32 + lq * 8];
#pragma unroll
        for (int mb = 0; mb < 4; mb++)
#pragma unroll
            for (int nb = 0; nb < 4; nb++)
                acc[mb][nb] = mfma16(af[mb], bf[nb], acc[mb][nb]);
        __syncthreads();
    }
#pragma unroll
    for (int mb = 0; mb < 4; mb++)
#pragma unroll
        for (int nb = 0; nb < 4; nb++)
#pragma unroll
            for (int r = 0; r < 4; r++) {
                int row = m0 + wm * 64 + mb * 16 + lq * 4 + r;
                int col = n0 + wn * 64 + nb * 16 + lm;
                if (STORE_F32)
                    ((float*)Cout)[(size_t)row * ldc + col] = acc[mb][nb][r];
                else
                    ((u16*)Cout)[(size_t)row * ldc + col] = f2b(acc[mb][nb][r]);
            }
}

// ---------------- Fused: RoPE in-place on Q,K  +  V transpose -> VT (B,H,D,S)
// block = (s-tile 64, bh)
__global__ __launch_bounds__(256) void rope_vt(u16* __restrict__ qkv, u16* __restrict__ VT) {
    __shared__ u16 T[64 * 136];
    const int tid = threadIdx.x;
    const int s0 = blockIdx.x * 64;
    const int bh = blockIdx.y;
    const int b = bh >> 4, h = bh & 15;
    // stage V tile into LDS (issue loads first; VALU rope below overlaps the latency)
#pragma unroll
    for (int p = 0; p < 4; p++) {
        int sl = p * 16 + (tid >> 4);
        int d0 = (tid & 15) * 8;
        *(us8*)&T[sl * 136 + d0] =
            *(const us8*)(qkv + ((size_t)(b * 2048 + s0 + sl)) * 6144 + 4096 + h * 128 + d0);
    }
    // RoPE on Q,K for this (b, h, s-range), vectorized us8, in place
#pragma unroll
    for (int p = 0; p < 2; p++) {
        int task = p * 256 + tid;      // 0..511
        int sl = task >> 3;            // 0..63
        int jg = task & 7;             // 0..7 (j block of 8)
        size_t base = ((size_t)(b * 2048 + s0 + sl)) * 6144 + h * 128 + jg * 8;
        us8 qlo = *(const us8*)(qkv + base);
        us8 qhi = *(const us8*)(qkv + base + 64);
        us8 klo = *(const us8*)(qkv + base + 2048);
        us8 khi = *(const us8*)(qkv + base + 2048 + 64);
        us8 oql, oqh, okl, okh;
        float s = (float)(s0 + sl);
#pragma unroll
        for (int e = 0; e < 8; e++) {
            int j = jg * 8 + e;
            float inv = __expf((float)j * (-9.210340371976184f / 64.f));
            float ang = s * inv;
            float sn, c;
            __sincosf(ang, &sn, &c);
            float q1 = b2f(qlo[e]), q2 = b2f(qhi[e]);
            oql[e] = f2b(q1 * c - q2 * sn);
            oqh[e] = f2b(q2 * c + q1 * sn);
            float k1 = b2f(klo[e]), k2 = b2f(khi[e]);
            okl[e] = f2b(k1 * c - k2 * sn);
            okh[e] = f2b(k2 * c + k1 * sn);
        }
        *(us8*)(qkv + base) = oql;
        *(us8*)(qkv + base + 64) = oqh;
        *(us8*)(qkv + base + 2048) = okl;
        *(us8*)(qkv + base + 2048 + 64) = okh;
    }
    __syncthreads();
    // write transposed V
#pragma unroll
    for (int p = 0; p < 4; p++) {
        int idx = p * 256 + tid;
        int d = idx & 127;
        int sg = idx >> 7;
        us8 v;
#pragma unroll
        for (int i = 0; i < 8; i++) v[i] = T[(sg * 8 + i) * 136 + d];
        *(us8*)&VT[((size_t)bh * 128 + d) * 2048 + s0 + sg * 8] = v;
    }
}

// ---------------- Flash attention v3: LDS-free; K/V fragments straight from global (L2-hot)
// block = (bh, 64-q tile, LPT); 4 waves x 16 q (q = wave*16 + lm); S^T trick + shuffle P-transpose
#define ATT_SCALE 0.08838834764831845f

__global__ __launch_bounds__(256) void attn_flash(const u16* __restrict__ qkv, const u16* __restrict__ VT,
                                                  u16* __restrict__ AO) {
    const int bh = blockIdx.x;          // x fastest -> bh%8 = XCD -> 4 heads/XCD = 4MB L2 set
    const int qt = 31 - blockIdx.y;     // heaviest blocks first
    const int b = bh >> 4, h = bh & 15;
    const int tid = threadIdx.x, lane = tid & 63, wave = tid >> 6;
    const int lm = lane & 15, lq = lane >> 4;
    const int q0 = qt * 64;

    // Q fragments (B-operand), RoPE already applied
    bf8_t qf[4];
    {
        const u16* Qrow = qkv + ((size_t)(b * 2048 + q0 + wave * 16 + lm)) * 6144 + h * 128;
#pragma unroll
        for (int ks = 0; ks < 4; ks++)
            qf[ks] = *(const bf8_t*)(Qrow + ks * 32 + lq * 8);
    }

    f32x4 Of[8] = {};                    // O^T accum
    float mrun = -3.0e38f, lrun = 0.f;

    const u16* Kbase = qkv + (size_t)b * 2048 * 6144 + 2048 + h * 128 + lq * 8;
    const u16* VTb = VT + (size_t)bh * 128 * 2048 + lq * 8;

    for (int kt = 0; kt <= qt; kt++) {
        const int k0 = kt * 64;
        // S^T = K · Q^T : lane holds S[q=lm][k = nb*16 + lq*4 + r]
        float sv[4][4];
#pragma unroll
        for (int nb = 0; nb < 4; nb++) {
            const u16* Krow = Kbase + (size_t)(k0 + nb * 16 + lm) * 6144;
            f32x4 a = {};
#pragma unroll
            for (int ks = 0; ks < 4; ks++) {
                bf8_t kf = *(const bf8_t*)(Krow + ks * 32);
                a = mfma16(kf, qf[ks], a);
            }
#pragma unroll
            for (int r = 0; r < 4; r++) sv[nb][r] = a[r] * ATT_SCALE;
        }
        if (kt == qt) {   // causal mask on diagonal tile
            int qloc = wave * 16 + lm;
#pragma unroll
            for (int nb = 0; nb < 4; nb++)
#pragma unroll
                for (int r = 0; r < 4; r++)
                    if (nb * 16 + lq * 4 + r > qloc) sv[nb][r] = -3.0e38f;
        }
        // online softmax (per-lane one q; reduce over 4 lq replicas)
        float mx = -3.0e38f;
#pragma unroll
        for (int nb = 0; nb < 4; nb++)
#pragma unroll
            for (int r = 0; r < 4; r++) mx = fmaxf(mx, sv[nb][r]);
        mx = fmaxf(mx, __shfl_xor(mx, 16, 64));
        mx = fmaxf(mx, __shfl_xor(mx, 32, 64));
        float mnew = fmaxf(mrun, mx);
        float alpha = __expf(mrun - mnew);
        float rs = 0.f;
        u64 pk[4];
#pragma unroll
        for (int nb = 0; nb < 4; nb++) {
            float e0 = __expf(sv[nb][0] - mnew), e1 = __expf(sv[nb][1] - mnew);
            float e2 = __expf(sv[nb][2] - mnew), e3 = __expf(sv[nb][3] - mnew);
            rs += (e0 + e1) + (e2 + e3);
            unsigned int lo = (unsigned int)f2b(e0) | ((unsigned int)f2b(e1) << 16);
            unsigned int hi = (unsigned int)f2b(e2) | ((unsigned int)f2b(e3) << 16);
            pk[nb] = (u64)lo | ((u64)hi << 32);
        }
        rs += __shfl_xor(rs, 16, 64);
        rs += __shfl_xor(rs, 32, 64);
        lrun = lrun * alpha + rs;
        mrun = mnew;
#pragma unroll
        for (int db = 0; db < 8; db++)
#pragma unroll
            for (int r = 0; r < 4; r++) Of[db][r] *= alpha;

        // P^T -> A-layout via shuffles; O^T += V^T · P
        const int slo = ((lq & 1) * 2) * 16 + lm;
        const int shi = slo + 16;
        const bool sel = (lq >> 1) != 0;
#pragma unroll
        for (int kk = 0; kk < 2; kk++) {
            u64 lo0 = __shfl(pk[2 * kk + 0], slo, 64);
            u64 lo1 = __shfl(pk[2 * kk + 1], slo, 64);
            u64 hi0 = __shfl(pk[2 * kk + 0], shi, 64);
            u64 hi1 = __shfl(pk[2 * kk + 1], shi, 64);
            union { u64 v[2]; bf8_t f; } pf;
            pf.v[0] = sel ? lo1 : lo0;
            pf.v[1] = sel ? hi1 : hi0;
            const u16* Vcol = VTb + k0 + kk * 32;
#pragma unroll
            for (int db = 0; db < 8; db++) {
                bf8_t vf = *(const bf8_t*)(Vcol + (size_t)(db * 16 + lm) * 2048);
                Of[db] = mfma16(vf, pf.f, Of[db]);
            }
        }
    }
    // epilogue: normalize, store O^T -> AO (B,S,HID)
    float invl = 1.f / lrun;
    size_t rowbase = (size_t)(b * 2048 + q0 + wave * 16 + lm) * 2048 + h * 128;
#pragma unroll
    for (int db = 0; db < 8; db++) {
        ushort4 o;
        o.x = f2b(Of[db][0] * invl);
        o.y = f2b(Of[db][1] * invl);
        o.z = f2b(Of[db][2] * invl);
        o.w = f2b(Of[db][3] * invl);
        *(ushort4*)(AO + rowbase + db * 16 + lq * 4) = o;
    }
}

extern "C" void kernel_launch(void* const* d_in, const int* in_sizes, int n_in,
                              void* d_out, int out_size, void* d_ws, size_t ws_size,
                              hipStream_t stream) {
    const float* x     = (const float*)d_in[0];
    const float* w_qkv = (const float*)d_in[1];
    const float* w_o   = (const float*)d_in[2];
    float* out = (float*)d_out;
    u16* ws = (u16*)d_ws;

    u16* qkvb  = ws;                    // 25,165,824
    u16* VT    = ws + 25165824;         //  8,388,608
    u16* AO    = ws + 33554432;         //  8,388,608
    u16* xb    = ws + 41943040;         //  8,388,608
    u16* wqkvb = ws + 50331648;         // 12,582,912
    u16* wob   = ws + 62914560;         //  4,194,304

    f32_to_bf16<<<4096, 256, 0, stream>>>(x, xb, 1048576);
    f32_to_bf16<<<6144, 256, 0, stream>>>(w_qkv, wqkvb, 1572864);
    f32_to_bf16<<<2048, 256, 0, stream>>>(w_o, wob, 524288);
    gemm_mfma_bt<0><<<dim3(48, 32), 256, 0, stream>>>(xb, wqkvb, qkvb, 4096, 6144, 2048, 6144);
    rope_vt<<<dim3(32, 32), 256, 0, stream>>>(qkvb, VT);
    attn_flash<<<dim3(32, 32), 256, 0, stream>>>(qkvb, VT, AO);
    gemm_mfma_bt<1><<<dim3(16, 32), 256, 0, stream>>>(AO, wob, out, 4096, 2048, 2048, 2048);
}

// Round 6
// 422.597 us; speedup vs baseline: 1.3863x; 1.3863x over previous
//
#include <hip/hip_runtime.h>
#include <hip/hip_bf16.h>

typedef unsigned short u16;
typedef unsigned long long u64;
typedef u16 us8 __attribute__((ext_vector_type(8)));
typedef __bf16 bf8_t __attribute__((ext_vector_type(8)));
typedef float f32x4 __attribute__((ext_vector_type(4)));

__device__ __forceinline__ float b2f(u16 u) {
    return __uint_as_float(((unsigned int)u) << 16);
}
__device__ __forceinline__ u16 f2b(float f) {
    union { __hip_bfloat16 h; u16 u; } v;
    v.h = __float2bfloat16(f);
    return v.u;
}
__device__ __forceinline__ f32x4 mfma16(bf8_t a, bf8_t b, f32x4 c) {
    return __builtin_amdgcn_mfma_f32_16x16x32_bf16(a, b, c, 0, 0, 0);
}
__device__ __forceinline__ void gload_lds16(const u16* g, u16* lds_base) {
    __builtin_amdgcn_global_load_lds((const __attribute__((address_space(1))) unsigned int*)g,
                                     (__attribute__((address_space(3))) unsigned int*)lds_base,
                                     16, 0, 0);
}

// ---------------- fp32 -> bf16 convert (8 elems/thread)
__global__ __launch_bounds__(256) void f32_to_bf16(const float* __restrict__ src,
                                                   u16* __restrict__ dst, int n8) {
    int idx = blockIdx.x * 256 + threadIdx.x;
    if (idx >= n8) return;
    float4 f0 = ((const float4*)src)[idx * 2];
    float4 f1 = ((const float4*)src)[idx * 2 + 1];
    us8 o;
    o[0] = f2b(f0.x); o[1] = f2b(f0.y); o[2] = f2b(f0.z); o[3] = f2b(f0.w);
    o[4] = f2b(f1.x); o[5] = f2b(f1.y); o[6] = f2b(f1.z); o[7] = f2b(f1.w);
    ((us8*)dst)[idx] = o;
}

// ---------------- bf16 MFMA GEMM: C[m,n] = sum_k A[m,k]*B[n,k]; 128x128x32 tiles
template<int STORE_F32>
__global__ __launch_bounds__(256) void gemm_mfma_bt(const u16* __restrict__ A, const u16* __restrict__ B,
                                                    void* __restrict__ Cout, int M, int N, int K, int ldc) {
    __shared__ u16 Alds[128 * 32];
    __shared__ u16 Blds[128 * 32];
    const int tid = threadIdx.x;
    const int lane = tid & 63, wave = tid >> 6;
    const int lm = lane & 15, lq = lane >> 4;
    const int wm = wave >> 1, wn = wave & 1;
    const int m0 = blockIdx.y * 128, n0 = blockIdx.x * 128;
    const int srow = lane >> 2;
    const int scol = (lane & 3) * 8;

    f32x4 acc[4][4] = {};

    for (int k0 = 0; k0 < K; k0 += 32) {
#pragma unroll
        for (int p = 0; p < 2; p++) {
            int rbase = wave * 16 + p * 64;
            gload_lds16(A + (size_t)(m0 + rbase + srow) * K + k0 + scol, &Alds[rbase * 32]);
            gload_lds16(B + (size_t)(n0 + rbase + srow) * K + k0 + scol, &Blds[rbase * 32]);
        }
        __syncthreads();
        bf8_t af[4], bf[4];
#pragma unroll
        for (int mb = 0; mb < 4; mb++)
            af[mb] = *(const bf8_t*)&Alds[(wm * 64 + mb * 16 + lm) * 32 + lq * 8];
#pragma unroll
        for (int nb = 0; nb < 4; nb++)
            bf[nb] = *(const bf8_t*)&Blds[(wn * 64 + nb * 16 + lm) * 32 + lq * 8];
#pragma unroll
        for (int mb = 0; mb < 4; mb++)
#pragma unroll
            for (int nb = 0; nb < 4; nb++)
                acc[mb][nb] = mfma16(af[mb], bf[nb], acc[mb][nb]);
        __syncthreads();
    }
#pragma unroll
    for (int mb = 0; mb < 4; mb++)
#pragma unroll
        for (int nb = 0; nb < 4; nb++)
#pragma unroll
            for (int r = 0; r < 4; r++) {
                int row = m0 + wm * 64 + mb * 16 + lq * 4 + r;
                int col = n0 + wn * 64 + nb * 16 + lm;
                if (STORE_F32)
                    ((float*)Cout)[(size_t)row * ldc + col] = acc[mb][nb][r];
                else
                    ((u16*)Cout)[(size_t)row * ldc + col] = f2b(acc[mb][nb][r]);
            }
}

// ---------------- Fused: RoPE in-place on Q,K  +  V transpose -> VT (B,H,D,S)
__global__ __launch_bounds__(256) void rope_vt(u16* __restrict__ qkv, u16* __restrict__ VT) {
    __shared__ u16 T[64 * 136];
    const int tid = threadIdx.x;
    const int s0 = blockIdx.x * 64;
    const int bh = blockIdx.y;
    const int b = bh >> 4, h = bh & 15;
#pragma unroll
    for (int p = 0; p < 4; p++) {
        int sl = p * 16 + (tid >> 4);
        int d0 = (tid & 15) * 8;
        *(us8*)&T[sl * 136 + d0] =
            *(const us8*)(qkv + ((size_t)(b * 2048 + s0 + sl)) * 6144 + 4096 + h * 128 + d0);
    }
#pragma unroll
    for (int p = 0; p < 2; p++) {
        int task = p * 256 + tid;
        int sl = task >> 3;
        int jg = task & 7;
        size_t base = ((size_t)(b * 2048 + s0 + sl)) * 6144 + h * 128 + jg * 8;
        us8 qlo = *(const us8*)(qkv + base);
        us8 qhi = *(const us8*)(qkv + base + 64);
        us8 klo = *(const us8*)(qkv + base + 2048);
        us8 khi = *(const us8*)(qkv + base + 2048 + 64);
        us8 oql, oqh, okl, okh;
        float s = (float)(s0 + sl);
#pragma unroll
        for (int e = 0; e < 8; e++) {
            int j = jg * 8 + e;
            float inv = __expf((float)j * (-9.210340371976184f / 64.f));
            float ang = s * inv;
            float sn, c;
            __sincosf(ang, &sn, &c);
            float q1 = b2f(qlo[e]), q2 = b2f(qhi[e]);
            oql[e] = f2b(q1 * c - q2 * sn);
            oqh[e] = f2b(q2 * c + q1 * sn);
            float k1 = b2f(klo[e]), k2 = b2f(khi[e]);
            okl[e] = f2b(k1 * c - k2 * sn);
            okh[e] = f2b(k2 * c + k1 * sn);
        }
        *(us8*)(qkv + base) = oql;
        *(us8*)(qkv + base + 64) = oqh;
        *(us8*)(qkv + base + 2048) = okl;
        *(us8*)(qkv + base + 2048 + 64) = okh;
    }
    __syncthreads();
#pragma unroll
    for (int p = 0; p < 4; p++) {
        int idx = p * 256 + tid;
        int d = idx & 127;
        int sg = idx >> 7;
        us8 v;
#pragma unroll
        for (int i = 0; i < 8; i++) v[i] = T[(sg * 8 + i) * 136 + d];
        *(us8*)&VT[((size_t)bh * 128 + d) * 2048 + s0 + sg * 8] = v;
    }
}

// ---------------- Flash attention v4: LDS-staged + register prefetch; 128-q blocks,
// each wave owns 2 q-groups of 16 (q = q0 + qg*64 + wave*16 + lm); S^T trick + shuffle P-transpose
#define ATT_SCALE 0.08838834764831845f

__global__ __launch_bounds__(256, 2) void attn_flash(const u16* __restrict__ qkv, const u16* __restrict__ VT,
                                                     u16* __restrict__ AO) {
    const int bh = blockIdx.x;
    const int qt = 15 - blockIdx.y;     // LPT: heaviest first
    const int b = bh >> 4, h = bh & 15;
    const int tid = threadIdx.x, lane = tid & 63, wave = tid >> 6;
    const int lm = lane & 15, lq = lane >> 4;
    const int q0 = qt * 128;

    __shared__ u16 Kt[64 * 136];        // [kpos][d]
    __shared__ u16 Vt[128 * 72];        // [d][kpos]

    // Q fragments (B-operand) for both q-groups
    bf8_t qf[2][4];
#pragma unroll
    for (int qg = 0; qg < 2; qg++) {
        const u16* Qrow = qkv + ((size_t)(b * 2048 + q0 + qg * 64 + wave * 16 + lm)) * 6144 + h * 128;
#pragma unroll
        for (int ks = 0; ks < 4; ks++)
            qf[qg][ks] = *(const bf8_t*)(Qrow + ks * 32 + lq * 8);
    }

    f32x4 Of[2][8] = {};
    float mrun[2] = {-3.0e38f, -3.0e38f}, lrun[2] = {0.f, 0.f};

    const u16* Kbase = qkv + (size_t)b * 2048 * 6144 + 2048 + h * 128;
    const u16* VTbase = VT + (size_t)bh * 128 * 2048;

    const int krow = tid >> 4;          // 0..15
    const int kcol = (tid & 15) * 8;
    const int vrow = tid >> 3;          // 0..31
    const int vcol = (tid & 7) * 8;
    const int ktmax = 2 * qt + 1;

    us8 kreg[4], vreg[4];
#pragma unroll
    for (int p = 0; p < 4; p++) {
        kreg[p] = *(const us8*)(Kbase + (size_t)(p * 16 + krow) * 6144 + kcol);
        vreg[p] = *(const us8*)(VTbase + (size_t)(p * 32 + vrow) * 2048 + vcol);
    }

    for (int kt = 0; kt <= ktmax; kt++) {
        __syncthreads();
#pragma unroll
        for (int p = 0; p < 4; p++) {
            *(us8*)&Kt[(p * 16 + krow) * 136 + kcol] = kreg[p];
            *(us8*)&Vt[(p * 32 + vrow) * 72 + vcol] = vreg[p];
        }
        __syncthreads();
        {   // prefetch next tile (clamped; final redundant reload discarded)
            int kn = (kt + 1 <= ktmax ? kt + 1 : ktmax) * 64;
#pragma unroll
            for (int p = 0; p < 4; p++) {
                kreg[p] = *(const us8*)(Kbase + (size_t)(kn + p * 16 + krow) * 6144 + kcol);
                vreg[p] = *(const us8*)(VTbase + (size_t)(p * 32 + vrow) * 2048 + kn + vcol);
            }
        }

        u64 pk[2][4];
        float alpha[2];
#pragma unroll
        for (int qg = 0; qg < 2; qg++) {
            // S^T = K · Q^T : lane holds S[q][k = nb*16 + lq*4 + r]
            float sv[4][4];
#pragma unroll
            for (int nb = 0; nb < 4; nb++) {
                f32x4 a = {};
#pragma unroll
                for (int ks = 0; ks < 4; ks++) {
                    bf8_t kf = *(const bf8_t*)&Kt[(nb * 16 + lm) * 136 + ks * 32 + lq * 8];
                    a = mfma16(kf, qf[qg][ks], a);
                }
#pragma unroll
                for (int r = 0; r < 4; r++) sv[nb][r] = a[r] * ATT_SCALE;
            }
            if (kt >= 2 * qt + qg) {   // diagonal or fully-masked tile
                int qglob = q0 + qg * 64 + wave * 16 + lm;
#pragma unroll
                for (int nb = 0; nb < 4; nb++)
#pragma unroll
                    for (int r = 0; r < 4; r++)
                        if (kt * 64 + nb * 16 + lq * 4 + r > qglob) sv[nb][r] = -3.0e38f;
            }
            // online softmax (per-lane one q; reduce over 4 lq replicas)
            float mx = -3.0e38f;
#pragma unroll
            for (int nb = 0; nb < 4; nb++)
#pragma unroll
                for (int r = 0; r < 4; r++) mx = fmaxf(mx, sv[nb][r]);
            mx = fmaxf(mx, __shfl_xor(mx, 16, 64));
            mx = fmaxf(mx, __shfl_xor(mx, 32, 64));
            float mnew = fmaxf(mrun[qg], mx);
            float a_ = __expf(mrun[qg] - mnew);
            float rs = 0.f;
#pragma unroll
            for (int nb = 0; nb < 4; nb++) {
                float e0 = __expf(sv[nb][0] - mnew), e1 = __expf(sv[nb][1] - mnew);
                float e2 = __expf(sv[nb][2] - mnew), e3 = __expf(sv[nb][3] - mnew);
                rs += (e0 + e1) + (e2 + e3);
                unsigned int lo = (unsigned int)f2b(e0) | ((unsigned int)f2b(e1) << 16);
                unsigned int hi = (unsigned int)f2b(e2) | ((unsigned int)f2b(e3) << 16);
                pk[qg][nb] = (u64)lo | ((u64)hi << 32);
            }
            rs += __shfl_xor(rs, 16, 64);
            rs += __shfl_xor(rs, 32, 64);
            lrun[qg] = lrun[qg] * a_ + rs;
            mrun[qg] = mnew;
            alpha[qg] = a_;
#pragma unroll
            for (int db = 0; db < 8; db++)
#pragma unroll
                for (int r = 0; r < 4; r++) Of[qg][db][r] *= a_;
        }

        // P^T -> A-layout via shuffles; O^T += V^T · P (V-frag shared across both qg)
        const int slo = ((lq & 1) * 2) * 16 + lm;
        const int shi = slo + 16;
        const bool sel = (lq >> 1) != 0;
#pragma unroll
        for (int kk = 0; kk < 2; kk++) {
            union { u64 v[2]; bf8_t f; } pf[2];
#pragma unroll
            for (int qg = 0; qg < 2; qg++) {
                u64 lo0 = __shfl(pk[qg][2 * kk + 0], slo, 64);
                u64 lo1 = __shfl(pk[qg][2 * kk + 1], slo, 64);
                u64 hi0 = __shfl(pk[qg][2 * kk + 0], shi, 64);
                u64 hi1 = __shfl(pk[qg][2 * kk + 1], shi, 64);
                pf[qg].v[0] = sel ? lo1 : lo0;
                pf[qg].v[1] = sel ? hi1 : hi0;
            }
#pragma unroll
            for (int db = 0; db < 8; db++) {
                bf8_t vf = *(const bf8_t*)&Vt[(db * 16 + lm) * 72 + kk * 32 + lq * 8];
                Of[0][db] = mfma16(vf, pf[0].f, Of[0][db]);
                Of[1][db] = mfma16(vf, pf[1].f, Of[1][db]);
            }
        }
    }
    // epilogue: normalize, store O^T -> AO (B,S,HID)
#pragma unroll
    for (int qg = 0; qg < 2; qg++) {
        float invl = 1.f / lrun[qg];
        size_t rowbase = (size_t)(b * 2048 + q0 + qg * 64 + wave * 16 + lm) * 2048 + h * 128;
#pragma unroll
        for (int db = 0; db < 8; db++) {
            ushort4 o;
            o.x = f2b(Of[qg][db][0] * invl);
            o.y = f2b(Of[qg][db][1] * invl);
            o.z = f2b(Of[qg][db][2] * invl);
            o.w = f2b(Of[qg][db][3] * invl);
            *(ushort4*)(AO + rowbase + db * 16 + lq * 4) = o;
        }
    }
}

extern "C" void kernel_launch(void* const* d_in, const int* in_sizes, int n_in,
                              void* d_out, int out_size, void* d_ws, size_t ws_size,
                              hipStream_t stream) {
    const float* x     = (const float*)d_in[0];
    const float* w_qkv = (const float*)d_in[1];
    const float* w_o   = (const float*)d_in[2];
    float* out = (float*)d_out;
    u16* ws = (u16*)d_ws;

    u16* qkvb  = ws;                    // 25,165,824
    u16* VT    = ws + 25165824;         //  8,388,608
    u16* AO    = ws + 33554432;         //  8,388,608
    u16* xb    = ws + 41943040;         //  8,388,608
    u16* wqkvb = ws + 50331648;         // 12,582,912
    u16* wob   = ws + 62914560;         //  4,194,304

    f32_to_bf16<<<4096, 256, 0, stream>>>(x, xb, 1048576);
    f32_to_bf16<<<6144, 256, 0, stream>>>(w_qkv, wqkvb, 1572864);
    f32_to_bf16<<<2048, 256, 0, stream>>>(w_o, wob, 524288);
    gemm_mfma_bt<0><<<dim3(48, 32), 256, 0, stream>>>(xb, wqkvb, qkvb, 4096, 6144, 2048, 6144);
    rope_vt<<<dim3(32, 32), 256, 0, stream>>>(qkvb, VT);
    attn_flash<<<dim3(32, 16), 256, 0, stream>>>(qkvb, VT, AO);
    gemm_mfma_bt<1><<<dim3(16, 32), 256, 0, stream>>>(AO, wob, out, 4096, 2048, 2048, 2048);
}